// Round 1
// baseline (24.735 us; speedup 1.0000x reference)
//
#include <hip/hip_runtime.h>

// Problem constants (fixed by reference setup_inputs)
constexpr int B_ = 32;
constexpr int S_ = 4096;
constexpr int D_ = 256;
constexpr int PAIRS_PER_BATCH = S_ - 1;                                   // 4095
constexpr int CHUNK = 16;                                                 // pairs per wave
constexpr int CHUNKS_PER_BATCH = (PAIRS_PER_BATCH + CHUNK - 1) / CHUNK;   // 256
constexpr int TOTAL_WAVES = B_ * CHUNKS_PER_BATCH;                        // 8192
constexpr int BLOCK = 256;
constexpr int WAVES_PER_BLOCK = BLOCK / 64;                               // 4
constexpr int GRID1 = TOTAL_WAVES / WAVES_PER_BLOCK;                      // 2048

// Kernel 1: each wave handles CHUNK consecutive pairs of one batch row.
// Only loads embedding rows adjacent to a masked pair (labels gate the load),
// reusing the previous row in registers when consecutive pairs are masked.
__global__ __launch_bounds__(BLOCK) void ccl_partial_kernel(
    const float* __restrict__ emb,
    const int* __restrict__ lab,
    float* __restrict__ partial) {
  const int wave = (blockIdx.x * BLOCK + threadIdx.x) >> 6;
  const int lane = threadIdx.x & 63;

  const int b = wave / CHUNKS_PER_BATCH;
  const int c = wave % CHUNKS_PER_BATCH;
  const int p0 = c * CHUNK;
  const int p1 = min(p0 + CHUNK, PAIRS_PER_BATCH);

  // Row s of this batch, as float4: 64 lanes x 16B = 1024B = one full row.
  const float4* __restrict__ rows =
      reinterpret_cast<const float4*>(emb + (size_t)b * S_ * D_);
  const int* __restrict__ lb = lab + b * S_;

  float wsum = 0.0f;
  bool have = false;       // cur holds row p's fragment
  float4 cur = make_float4(0.f, 0.f, 0.f, 0.f);

  for (int p = p0; p < p1; ++p) {
    const int l0 = lb[p];
    const int l1 = lb[p + 1];
    const bool m = (l0 != 0) && (l0 == l1);   // lane-uniform
    if (!m) { have = false; continue; }

    if (!have) cur = rows[(size_t)p * (D_ / 4) + lane];
    float4 nxt = rows[(size_t)(p + 1) * (D_ / 4) + lane];

    const float dx = cur.x - nxt.x;
    const float dy = cur.y - nxt.y;
    const float dz = cur.z - nxt.z;
    const float dw = cur.w - nxt.w;
    float s = dx * dx + dy * dy + dz * dz + dw * dw;

    // 64-lane butterfly reduce
    #pragma unroll
    for (int xm = 1; xm < 64; xm <<= 1) s += __shfl_xor(s, xm, 64);

    wsum += sqrtf(s);
    cur = nxt;
    have = true;
  }

  if (lane == 0) partial[wave] = wsum;
}

// Kernel 2: deterministic fixed-order reduction of the 8192 wave partials.
__global__ __launch_bounds__(BLOCK) void ccl_reduce_kernel(
    const float* __restrict__ partial, float* __restrict__ out) {
  float s = 0.0f;
  for (int i = threadIdx.x; i < TOTAL_WAVES; i += BLOCK) s += partial[i];

  #pragma unroll
  for (int xm = 1; xm < 64; xm <<= 1) s += __shfl_xor(s, xm, 64);

  __shared__ float lds[WAVES_PER_BLOCK];
  const int lane = threadIdx.x & 63;
  const int w = threadIdx.x >> 6;
  if (lane == 0) lds[w] = s;
  __syncthreads();

  if (threadIdx.x == 0) {
    float t = 0.0f;
    #pragma unroll
    for (int i = 0; i < WAVES_PER_BLOCK; ++i) t += lds[i];
    out[0] = t / (float)((long long)B_ * S_);
  }
}

extern "C" void kernel_launch(void* const* d_in, const int* in_sizes, int n_in,
                              void* d_out, int out_size, void* d_ws, size_t ws_size,
                              hipStream_t stream) {
  const float* emb = (const float*)d_in[0];
  const int* lab = (const int*)d_in[1];
  float* out = (float*)d_out;
  float* partial = (float*)d_ws;   // TOTAL_WAVES floats = 32 KiB

  ccl_partial_kernel<<<GRID1, BLOCK, 0, stream>>>(emb, lab, partial);
  ccl_reduce_kernel<<<1, BLOCK, 0, stream>>>(partial, out);
}

// Round 2
// 22.395 us; speedup vs baseline: 1.1045x; 1.1045x over previous
//
#include <hip/hip_runtime.h>

// Problem constants (fixed by reference setup_inputs)
constexpr int B_ = 32;
constexpr int S_ = 4096;
constexpr int D_ = 256;
constexpr int PAIRS_PER_BATCH = S_ - 1;                                   // 4095
constexpr int CHUNK = 16;                                                 // pairs per wave
constexpr int CHUNKS_PER_BATCH = (PAIRS_PER_BATCH + CHUNK - 1) / CHUNK;   // 256
constexpr int TOTAL_WAVES = B_ * CHUNKS_PER_BATCH;                        // 8192
constexpr int BLOCK = 256;
constexpr int WAVES_PER_BLOCK = BLOCK / 64;                               // 4
constexpr int GRID1 = TOTAL_WAVES / WAVES_PER_BLOCK;                      // 2048

// Kernel 1: each wave handles CHUNK consecutive pairs of one batch row.
// Phase A: one coalesced label read + ballot -> wave-uniform pair mask.
// Phase B: issue ALL needed row loads up front (<=17 independent float4
//          loads per wave -> high MLP).
// Phase C: per masked pair, diff + 64-lane butterfly + sqrt, accumulate.
__global__ __launch_bounds__(BLOCK) void ccl_partial_kernel(
    const float* __restrict__ emb,
    const int* __restrict__ lab,
    float* __restrict__ partial) {
  const int wave = (blockIdx.x * BLOCK + threadIdx.x) >> 6;
  const int lane = threadIdx.x & 63;

  const int b = wave / CHUNKS_PER_BATCH;
  const int c = wave % CHUNKS_PER_BATCH;
  const int p0 = c * CHUNK;
  const int npairs = min(CHUNK, PAIRS_PER_BATCH - p0);   // 16, or 15 for last chunk

  const float4* __restrict__ rows =
      reinterpret_cast<const float4*>(emb + (size_t)b * S_ * D_);
  const int* __restrict__ lb = lab + b * S_;

  // --- Phase A: mask via ballot (one coalesced 68B label read per wave) ---
  int lv = 0;
  if (lane <= npairs) lv = lb[p0 + lane];     // labels p0 .. p0+npairs
  const int nl = __shfl_down(lv, 1, 64);      // label at p0+lane+1
  const bool m = (lane < npairs) && (lv != 0) && (lv == nl);
  const unsigned long long mask = __ballot(m);          // bit i = pair p0+i masked
  if (mask == 0ULL) {
    if (lane == 0) partial[wave] = 0.0f;
    return;
  }
  const unsigned long long rowmask = mask | (mask << 1); // bit i = row p0+i needed

  // --- Phase B: issue all needed row loads (independent, in flight together) ---
  float4 r[CHUNK + 1];
  #pragma unroll
  for (int i = 0; i <= CHUNK; ++i) {
    if ((rowmask >> i) & 1ULL) {
      r[i] = rows[(size_t)(p0 + i) * (D_ / 4) + lane];
    }
  }

  // --- Phase C: reduce each masked pair ---
  float wsum = 0.0f;
  #pragma unroll
  for (int i = 0; i < CHUNK; ++i) {
    if ((mask >> i) & 1ULL) {
      const float dx = r[i].x - r[i + 1].x;
      const float dy = r[i].y - r[i + 1].y;
      const float dz = r[i].z - r[i + 1].z;
      const float dw = r[i].w - r[i + 1].w;
      float s = dx * dx + dy * dy + dz * dz + dw * dw;
      #pragma unroll
      for (int xm = 1; xm < 64; xm <<= 1) s += __shfl_xor(s, xm, 64);
      wsum += sqrtf(s);
    }
  }

  if (lane == 0) partial[wave] = wsum;
}

// Kernel 2: deterministic fixed-order reduction of the 8192 wave partials.
__global__ __launch_bounds__(BLOCK) void ccl_reduce_kernel(
    const float* __restrict__ partial, float* __restrict__ out) {
  float s = 0.0f;
  for (int i = threadIdx.x; i < TOTAL_WAVES; i += BLOCK) s += partial[i];

  #pragma unroll
  for (int xm = 1; xm < 64; xm <<= 1) s += __shfl_xor(s, xm, 64);

  __shared__ float lds[WAVES_PER_BLOCK];
  const int lane = threadIdx.x & 63;
  const int w = threadIdx.x >> 6;
  if (lane == 0) lds[w] = s;
  __syncthreads();

  if (threadIdx.x == 0) {
    float t = 0.0f;
    #pragma unroll
    for (int i = 0; i < WAVES_PER_BLOCK; ++i) t += lds[i];
    out[0] = t / (float)((long long)B_ * S_);
  }
}

extern "C" void kernel_launch(void* const* d_in, const int* in_sizes, int n_in,
                              void* d_out, int out_size, void* d_ws, size_t ws_size,
                              hipStream_t stream) {
  const float* emb = (const float*)d_in[0];
  const int* lab = (const int*)d_in[1];
  float* out = (float*)d_out;
  float* partial = (float*)d_ws;   // TOTAL_WAVES floats = 32 KiB

  ccl_partial_kernel<<<GRID1, BLOCK, 0, stream>>>(emb, lab, partial);
  ccl_reduce_kernel<<<1, BLOCK, 0, stream>>>(partial, out);
}